// Round 5
// baseline (836.570 us; speedup 1.0000x reference)
//
#include <hip/hip_runtime.h>
#include <hip/hip_fp16.h>
#include <stdint.h>

// sLSTM cell, T=512, B=16, H=4 heads, D=256, G=4 gates. fp32 in/out.
//
// R5b = R5 with the launder fixed: gfx950 backend can't tie a 128-bit
// uint4 as one "+v" operand ("tied indirect register inputs"); launder
// each 32-bit component instead (scalar "+v" is the form R4b compiled).
//
// Rationale (from R4b counters): VGPR_Count=84 -> the 128-u32 weight
// array was scratch-demoted (rule #20), so every step re-read 512 B/lane
// of weights: ~17 GB over the run ~ 24.6 TB/s sustained ~ 70% of the L2
// ceiling. Kernel was L2-BW-bound on weight re-streaming (invisible in
// FETCH_SIZE because the blob is L2-resident). Fix: 32 named uint4 vars,
// loaded straight-line, laundered once -> no array, no demotion, no remat.
//
// Carried from R4b (proven passing, 683 us):
//  - Wave-autonomous zero-barrier structure: 64 chains x 16 waves,
//    wave ww owns dout = ww*16+jl, lane = jl*4+kq computes all 4 gates
//    over k-quarter kq (128 fdot2), 2-round DPP quad butterfly.
//  - Exchange: self-validating u32 (hi16=f16(h), lo16=tag=t+1), 2-slot
//    ping-pong, __hip_atomic_load/store AGENT relaxed, spin-capped.
//  - LDS: per-wave 144-u32 padded pack row, wave-synchronous only.

#define NTS 512
#define OUTS_ELEMS (NTS * 16 * 1024)   // 8388608 floats of `outs`
#define SPIN_CAP 8192

typedef _Float16 half2v __attribute__((ext_vector_type(2)));

__device__ __forceinline__ float fdot2f(uint32_t a, uint32_t b, float c) {
#if __has_builtin(__builtin_amdgcn_fdot2)
  union U { uint32_t u; half2v h; };
  U ua, ub; ua.u = a; ub.u = b;
  return __builtin_amdgcn_fdot2(ua.h, ub.h, c, false);
#else
  __half2 ha, hb;
  *(uint32_t*)&ha = a; *(uint32_t*)&hb = b;
  float2 fa = __half22float2(ha), fb = __half22float2(hb);
  return fmaf(fa.y, fb.y, fmaf(fa.x, fb.x, c));
#endif
}

// quad_perm DPP cross-lane swaps within each lane-quad:
//   xor1 = [1,0,3,2] -> ctrl 0xB1 ; xor2 = [2,3,0,1] -> ctrl 0x4E
__device__ __forceinline__ float qxor1(float v) {
  return __int_as_float(__builtin_amdgcn_update_dpp(
      0, __float_as_int(v), 0xB1, 0xF, 0xF, true));
}
__device__ __forceinline__ float qxor2(float v) {
  return __int_as_float(__builtin_amdgcn_update_dpp(
      0, __float_as_int(v), 0x4E, 0xF, 0xF, true));
}

// Packed blob (u32 index): ((W*32 + mm)*64 + lane)*4 + dd
//   W = head*16 + ww (wave-in-chain), lane = jl*4 + kq, n = mm*4 + dd:
//   g = n>>5, p = n&31. dout = ww*16 + jl, din = kq*64 + 2p + e.
//   Weff[h,g,dout,din] = rk[h, (din%64)*4+g, dout>>6, (dout&63)*4 + din>>6]
__global__ void repack_weights(const float* __restrict__ rk,
                               uint32_t* __restrict__ wp) {
  int tid = blockIdx.x * 256 + threadIdx.x;   // [0, 524288)
  int dd   = tid & 3;
  int lane = (tid >> 2) & 63;
  int mm   = (tid >> 8) & 31;
  int W    = tid >> 13;                        // head*16 + ww
  int head = W >> 4, ww = W & 15;
  int jl = lane >> 2, kq = lane & 3;
  int n = mm * 4 + dd;
  int g = n >> 5, p = n & 31;
  int dout = ww * 16 + jl;
  uint32_t word = 0;
  #pragma unroll
  for (int e = 0; e < 2; ++e) {
    int klo = 2 * p + e;                       // din % 64
    float v = rk[head * 262144 + (klo * 4 + g) * 1024 +
                 (dout >> 6) * 256 + (dout & 63) * 4 + kq];
    word |= (uint32_t)__half_as_ushort(__float2half(v)) << (16 * e);
  }
  wp[tid] = word;
}

__global__ __launch_bounds__(256, 1) void slstm_main(
    const float* __restrict__ x, const float* __restrict__ bias,
    const uint32_t* __restrict__ wp, uint32_t* hex,
    float* __restrict__ out) {
  // Per-wave padded h-pack row: 4 quarters x (32 words + 4 pad) = 144 u32.
  // Wave-synchronous only (write own 2 pair-words, read own quarter).
  __shared__ __align__(16) uint32_t lhp[4][144];

  // XCD swizzle (perf only; correctness never depends on placement).
  const int bid = blockIdx.x;
  const int xcd = bid & 7, yy = bid >> 3;
  const int q4 = yy & 3, ii = yy >> 2;
  const int cc = xcd * 8 + ii;                 // chain [0,64)
  const int b = cc >> 2, head = cc & 3;
  const int lane = threadIdx.x & 63, w = threadIdx.x >> 6;
  const int ww = q4 * 4 + w;                   // wave-in-chain [0,16)
  const int jl = lane >> 2, kq = lane & 3;
  const int dout = ww * 16 + jl;               // this lane's output dim

  // ---- register-resident weights: 32 named uint4 = 128 u32 = 256 f16 ----
  const uint4* wp4 = (const uint4*)wp;
  const int base = (head * 16 + ww) * 2048 + lane;
#define LDW(i) uint4 wv##i = wp4[base + (i) * 64]
  LDW(0);  LDW(1);  LDW(2);  LDW(3);  LDW(4);  LDW(5);  LDW(6);  LDW(7);
  LDW(8);  LDW(9);  LDW(10); LDW(11); LDW(12); LDW(13); LDW(14); LDW(15);
  LDW(16); LDW(17); LDW(18); LDW(19); LDW(20); LDW(21); LDW(22); LDW(23);
  LDW(24); LDW(25); LDW(26); LDW(27); LDW(28); LDW(29); LDW(30); LDW(31);
#undef LDW
  // Launder each named var ONCE, per 32-bit component (gfx950 backend
  // rejects tied 128-bit asm operands). Compiler can neither remat the
  // loads inside the t-loop nor demote to scratch (no array exists).
#define LAU(i) asm volatile("" : "+v"(wv##i.x), "+v"(wv##i.y), \
                                 "+v"(wv##i.z), "+v"(wv##i.w))
  LAU(0);  LAU(1);  LAU(2);  LAU(3);  LAU(4);  LAU(5);  LAU(6);  LAU(7);
  LAU(8);  LAU(9);  LAU(10); LAU(11); LAU(12); LAU(13); LAU(14); LAU(15);
  LAU(16); LAU(17); LAU(18); LAU(19); LAU(20); LAU(21); LAU(22); LAU(23);
  LAU(24); LAU(25); LAU(26); LAU(27); LAU(28); LAU(29); LAU(30); LAU(31);
#undef LAU

  // bias layout quirk (proven in R2): bflat index = g*1024 + head*256 + j
  const float bg = bias[kq * 1024 + head * 256 + dout];
  const int xoff0 = b * 4096 + kq * 1024 + head * 256 + dout;
  float xv = x[xoff0];                         // x_t for t = 0

  const int rd_base = cc * 256 + lane * 4;     // 4 words this lane polls
  const int wr_idx  = cc * 256 + dout;         // word kq==0 lanes publish
  const int out_off = b * 1024 + head * 256 + dout;
  const bool pub = (kq == 0);

  uint32_t* lrow = &lhp[w][0];
  const int widx = (lane >> 4) * 36 + ((2 * lane) & 31);  // write slot (u32)

  float hs = 0.f, cs = 0.f, nns = 0.f, ms = 0.f;

  #pragma unroll 1
  for (int t = 0; t < NTS; ++t) {
    // x+bias injected pre-butterfly: lane kq contributes gate kq exactly once
    float xb = xv + bg;
    float A0 = (kq == 0) ? xb : 0.f;
    float A1 = (kq == 1) ? xb : 0.f;
    float A2 = (kq == 2) ? xb : 0.f;
    float A3 = (kq == 3) ? xb : 0.f;
    float xn = 0.f;
    if (t > 0) {
      // --- acquire h_{t-1}: 4 agent-scope word polls, self-validating ---
      // tag of step s is s+1, so tg = (t-1)+1 = t; stale words never match.
      const uint32_t tg = (uint32_t)t;
      const uint32_t* sp = hex + ((t - 1) & 1) * 16384 + rd_base;
      uint32_t v0, v1, v2, v3; int spins = 0;
      for (;;) {
        v0 = __hip_atomic_load(sp + 0, __ATOMIC_RELAXED, __HIP_MEMORY_SCOPE_AGENT);
        v1 = __hip_atomic_load(sp + 1, __ATOMIC_RELAXED, __HIP_MEMORY_SCOPE_AGENT);
        v2 = __hip_atomic_load(sp + 2, __ATOMIC_RELAXED, __HIP_MEMORY_SCOPE_AGENT);
        v3 = __hip_atomic_load(sp + 3, __ATOMIC_RELAXED, __HIP_MEMORY_SCOPE_AGENT);
        int ok = ((v0 & 0xffffu) == tg) & ((v1 & 0xffffu) == tg) &
                 ((v2 & 0xffffu) == tg) & ((v3 & 0xffffu) == tg);
        if (__all(ok)) break;
        if (++spins > SPIN_CAP) break;         // fail-fast, never hang
      }
      // prefetch next step's x now; drains during dots
      if (t < NTS - 1) xn = x[xoff0 + (t + 1) * 65536];
      // pack h[4L..4L+3] into 2 pair-words, write to own wave's LDS row
      uint32_t p0 = (v0 >> 16) | (v1 & 0xffff0000u);
      uint32_t p1 = (v2 >> 16) | (v3 & 0xffff0000u);
      *(uint64_t*)&lrow[widx] = ((uint64_t)p1 << 32) | (uint64_t)p0;
      // read own k-quarter: 8x ds_read_b128, quad-broadcast addresses.
      // Gate block g, chunk c uses named var wv{g*8+c} (blob mm = n>>2).
      const uint4* rp = (const uint4*)&lrow[kq * 36];
#define DOTSTEP(c, W0, W1, W2, W3)                  \
      do {                                          \
        uint4 hw = rp[c];                           \
        A0 = fdot2f(W0.x, hw.x, A0);                \
        A0 = fdot2f(W0.y, hw.y, A0);                \
        A0 = fdot2f(W0.z, hw.z, A0);                \
        A0 = fdot2f(W0.w, hw.w, A0);                \
        A1 = fdot2f(W1.x, hw.x, A1);                \
        A1 = fdot2f(W1.y, hw.y, A1);                \
        A1 = fdot2f(W1.z, hw.z, A1);                \
        A1 = fdot2f(W1.w, hw.w, A1);                \
        A2 = fdot2f(W2.x, hw.x, A2);                \
        A2 = fdot2f(W2.y, hw.y, A2);                \
        A2 = fdot2f(W2.z, hw.z, A2);                \
        A2 = fdot2f(W2.w, hw.w, A2);                \
        A3 = fdot2f(W3.x, hw.x, A3);                \
        A3 = fdot2f(W3.y, hw.y, A3);                \
        A3 = fdot2f(W3.z, hw.z, A3);                \
        A3 = fdot2f(W3.w, hw.w, A3);                \
      } while (0)
      DOTSTEP(0, wv0, wv8,  wv16, wv24);
      DOTSTEP(1, wv1, wv9,  wv17, wv25);
      DOTSTEP(2, wv2, wv10, wv18, wv26);
      DOTSTEP(3, wv3, wv11, wv19, wv27);
      DOTSTEP(4, wv4, wv12, wv20, wv28);
      DOTSTEP(5, wv5, wv13, wv21, wv29);
      DOTSTEP(6, wv6, wv14, wv22, wv30);
      DOTSTEP(7, wv7, wv15, wv23, wv31);
#undef DOTSTEP
    } else {
      xn = x[xoff0 + 65536];
    }

    // quad butterfly (pure VALU): every lane gets full-k gate pre-acts
    A0 += qxor1(A0); A0 += qxor2(A0);
    A1 += qxor1(A1); A1 += qxor2(A1);
    A2 += qxor1(A2); A2 += qxor2(A2);
    A3 += qxor1(A3); A3 += qxor2(A3);

    // state update (matches reference; all(n==0) <=> t==0).
    // Fast forms: err ~1e-7 << f16-exchange noise (~1e-3).
    float ri = A0, rf = A1, rz = A2, ro = A3;
    float lsf = fminf(rf, 0.f) - __logf(1.f + __expf(-fabsf(rf)));
    float lf = ms + lsf;
    float mnew = (t == 0) ? ri : fmaxf(ri, lf);
    float ig = __expf(ri - mnew);
    float fg = __expf(lf - mnew);
    float e2z = __expf(2.f * rz);
    float tz = 1.f - 2.f / (e2z + 1.f);          // tanh(rz)
    float cnew = fg * cs + ig * tz;
    float nnew = fg * hs + ig;                   // reference uses h here
    float hnew = cnew / ((1.f + __expf(-ro)) * nnew);  // og*cnew/nnew fused
    hs = hnew; cs = cnew; nns = nnew; ms = mnew;

    unsigned short hf = __half_as_ushort(__float2half(hnew));
    if (pub) {
      // publish FIRST (critical path), then the out store
      uint32_t wword = ((uint32_t)hf << 16) | (uint32_t)(t + 1);
      __hip_atomic_store(hex + (t & 1) * 16384 + wr_idx, wword,
                         __ATOMIC_RELAXED, __HIP_MEMORY_SCOPE_AGENT);
      out[t * 16384 + out_off] = hnew;
    }
    xv = xn;
  }

  // final_state: stack (h, c, n, m)
  if (pub) {
    float* fs = out + OUTS_ELEMS;
    fs[out_off] = hs;
    fs[16384 + out_off] = cs;
    fs[32768 + out_off] = nns;
    fs[49152 + out_off] = ms;
  }
}

extern "C" void kernel_launch(void* const* d_in, const int* in_sizes, int n_in,
                              void* d_out, int out_size, void* d_ws,
                              size_t ws_size, hipStream_t stream) {
  const float* x    = (const float*)d_in[0];  // (512,16,4096)
  const float* rk   = (const float*)d_in[1];  // (4,256,4,256)
  const float* bias = (const float*)d_in[2];  // (4,4,256)
  uint32_t* wp  = (uint32_t*)d_ws;                         // 2 MB packed f16
  uint32_t* hex = (uint32_t*)((char*)d_ws + (1u << 21));   // 128 KB exchange
  float* out = (float*)d_out;

  repack_weights<<<2048, 256, 0, stream>>>(rk, wp);
  slstm_main<<<256, 256, 0, stream>>>(x, bias, wp, hex, out);
}